// Round 1
// 400.801 us; speedup vs baseline: 1.4463x; 1.4463x over previous
//
#include <hip/hip_runtime.h>
#include <hip/hip_bf16.h>

typedef __attribute__((ext_vector_type(8))) short bf16x8;
typedef __attribute__((ext_vector_type(16))) float f32x16;
typedef __attribute__((ext_vector_type(4))) float f32x4;
typedef __attribute__((ext_vector_type(4))) unsigned int uint4v;
typedef unsigned short ushort_t;

#define N_NODES 16384
#define HD 128
#define NOUT 384
#define PART_ELEMS 6291456    // 16384*384
// packed B: pk[it][g][c][oct][l31][j]  it:0..129 (128,129 = U1,U2 tails)
//   byte offset = ((it*12+g)*16 + c*2 + oct)*512 + l31*16 + j*2 ; per-it = 98304 B

static __device__ __forceinline__ ushort_t f2bf(float f) {
  __hip_bfloat16 b = __float2bfloat16(f);
  return *reinterpret_cast<ushort_t*>(&b);
}

// ---------------- fused prep (384 threads/block) — unchanged ----------------
__global__ void prep_all(const float* __restrict__ A, const float* __restrict__ U1,
                         const float* __restrict__ U2, const float* __restrict__ nh,
                         ushort_t* __restrict__ pk, ushort_t* __restrict__ h1,
                         ushort_t* __restrict__ h2, float* __restrict__ h1tf) {
  __shared__ __align__(16) char smem[49152];
  const int b = blockIdx.x;
  const int t = threadIdx.x;

  if (b < 260) {
    short* spk = reinterpret_cast<short*>(smem);
    const int half = b & 1;
    const int gg = t >> 5, ll = t & 31;
    if (b < 256) {
      const int it = b >> 1;
      const size_t krow0 = (size_t)it * 128 + half * 64;
#pragma unroll 4
      for (int kl = 0; kl < 64; ++kl) {
        float v = A[(krow0 + kl) * NOUT + t];
        int cl = kl >> 4, oc = (kl >> 3) & 1, j = kl & 7;
        spk[(gg * 8 + cl * 2 + oc) * 256 + ll * 8 + j] = f2bf(v);
      }
    } else {
      const int u = (b - 256) >> 1;
      const float* U = u ? U2 : U1;
#pragma unroll 4
      for (int kl = 0; kl < 64; ++kl) {
        float v = U[(size_t)t * HD + half * 64 + kl];
        int cl = kl >> 4, oc = (kl >> 3) & 1, j = kl & 7;
        spk[(gg * 8 + cl * 2 + oc) * 256 + ll * 8 + j] = f2bf(v);
      }
    }
    __syncthreads();
    const int it_out = (b < 256) ? (b >> 1) : (128 + ((b - 256) >> 1));
    const int f = t * 64;
    const int g = f >> 11;
    const int inner = f & 2047;
    ushort_t* dst = pk + (size_t)it_out * 49152 + g * 4096 + half * 2048 + inner;
    const uint4* src = reinterpret_cast<const uint4*>(spk + f);
    uint4* d4 = reinterpret_cast<uint4*>(dst);
#pragma unroll
    for (int q = 0; q < 8; ++q) d4[q] = src[q];
  } else {
    if (t < 256) {
      float (*sm)[65] = reinterpret_cast<float(*)[65]>(smem);
      const int g = b - 260;            // 0..511
      const int mt = g & 255, jt = g >> 8;
      const int tx = t & 63, ty = t >> 6;
      const int m0 = mt * 64, j0 = jt * 64;
#pragma unroll
      for (int s = 0; s < 16; ++s) {
        int mm = ty + s * 4;
        float f1 = nh[(size_t)(m0 + mm) * 256 + j0 + tx];
        float f2 = nh[(size_t)(m0 + mm) * 256 + 128 + j0 + tx];
        h1[(size_t)(m0 + mm) * HD + j0 + tx] = f2bf(f1);
        h2[(size_t)(m0 + mm) * HD + j0 + tx] = f2bf(f2);
        sm[mm][tx] = f1;
      }
      __syncthreads();
#pragma unroll
      for (int s = 0; s < 16; ++s) {
        int jj = ty + s * 4;
        h1tf[(size_t)(j0 + jj) * N_NODES + m0 + tx] = sm[tx][jj];   // f32 transposed h1
      }
    }
  }
}

// ---------------- main GEMM: swapped-operand (transposed) accumulation ----------------
// accT[n,m] per lane: col(lane&31) = m-local, row(reg) = n-local.
// Per slice i: P^T = sum_c mfma(A=bb[c] (B_i^T frag), B=h2u[ms][c] (h2^T frag)), then
// acc[ms][r] += h1[m(lane), i] * P[r]  — h1 is ONE scalar per lane (coalesced f32 load).
// Wave tile 64m x 32n (acc 32 regs, h2u 64). Block = 8 waves (4wm x 2wn) = 256m x 64n.
// grid = 64 Mt x 6 Nt x 2 ks = 768 blocks @ 1 block/CU resident -> exactly 3 balanced rounds.
__global__ __launch_bounds__(512, 2)
void gemm_kernel(const ushort_t* __restrict__ pk, const ushort_t* __restrict__ h1bf,
                 const ushort_t* __restrict__ h2bf, const float* __restrict__ h1tf,
                 const float* __restrict__ u2b, float* __restrict__ part) {
  const int tid = threadIdx.x;
  const int bid = blockIdx.x;
  // XCD-clustering swizzle (bijective: 768 = 8*96): each XCD sees <=2 (Nt,ks) slabs.
  const int v  = (bid & 7) * 96 + (bid >> 3);
  const int Mt = v & 63;
  const int q  = v >> 6;        // 0..11
  const int Nt = q >> 1;
  const int ks = q & 1;

  const int lane = tid & 63, wv = tid >> 6;
  const int l31 = lane & 31, oct = lane >> 5;
  const int wm = wv >> 1, wn = wv & 1;          // 4m x 2n wave grid
  const int mbase = Mt * 256 + wm * 64;
  const int n0w = Nt * 64 + wn * 32;
  const int g = Nt * 2 + wn;                    // 32-col group in pk

  // resident h2 fragments (used as MFMA B-operand): rows mbase+ms*32+l31
  uint4v h2u[2][8];
#pragma unroll
  for (int ms = 0; ms < 2; ++ms) {
    const ushort_t* hp = h2bf + (size_t)(mbase + ms * 32 + l31) * HD + oct * 8;
#pragma unroll
    for (int c = 0; c < 8; ++c)
      h2u[ms][c] = *reinterpret_cast<const uint4v*>(hp + c * 16);
  }

  // acc init (transposed layout): acc[ms][r] = out[mbase+ms*32+l31][n0w+(r&3)+8*(r>>2)+4*oct]
  f32x16 acc[2];
  if (ks) {
#pragma unroll
    for (int qq = 0; qq < 4; ++qq) {
      f32x4 bq = *reinterpret_cast<const f32x4*>(u2b + n0w + 8 * qq + 4 * oct);
#pragma unroll
      for (int j = 0; j < 4; ++j) { acc[0][qq * 4 + j] = bq[j]; acc[1][qq * 4 + j] = bq[j]; }
    }
  } else {
    acc[0] = (f32x16)(0.0f);
    acc[1] = (f32x16)(0.0f);
  }

  const int it0 = ks ? 65 : 0;
  const int it1 = ks ? 128 : 65;

  const char* pb = reinterpret_cast<const char*>(pk) +
                   (size_t)it0 * 98304 + (size_t)(g * 16 + oct) * 512 + (size_t)l31 * 16;
  const float* ph1 = h1tf + (size_t)it0 * N_NODES + mbase + l31;

#pragma unroll 2
  for (int it = it0; it < it1; ++it) {
    uint4v bb[8];
#pragma unroll
    for (int c = 0; c < 8; ++c)
      bb[c] = *reinterpret_cast<const uint4v*>(pb + c * 1024);
    float s0 = ph1[0];
    float s1 = ph1[32];
    f32x16 P0 = (f32x16)(0.0f), P1 = (f32x16)(0.0f);
#pragma unroll
    for (int c = 0; c < 8; ++c) {
      bf16x8 bfr = __builtin_bit_cast(bf16x8, bb[c]);
      P0 = __builtin_amdgcn_mfma_f32_32x32x16_bf16(
          bfr, __builtin_bit_cast(bf16x8, h2u[0][c]), P0, 0, 0, 0);
      P1 = __builtin_amdgcn_mfma_f32_32x32x16_bf16(
          bfr, __builtin_bit_cast(bf16x8, h2u[1][c]), P1, 0, 0, 0);
    }
#pragma unroll
    for (int r = 0; r < 16; ++r) {
      acc[0][r] += s0 * P0[r];
      acc[1][r] += s1 * P1[r];
    }
    pb += 98304;
    ph1 += N_NODES;
  }

  if (ks) {
    // U1 tail (it=128): accT += mfma(A=bb, B=h1 fragment)
    const char* bt = reinterpret_cast<const char*>(pk) +
                     (size_t)128 * 98304 + (size_t)(g * 16 + oct) * 512 + (size_t)l31 * 16;
#pragma unroll
    for (int c = 0; c < 8; ++c) {
      bf16x8 bfr = __builtin_bit_cast(bf16x8, *reinterpret_cast<const uint4v*>(bt + c * 1024));
#pragma unroll
      for (int ms = 0; ms < 2; ++ms) {
        bf16x8 a = *reinterpret_cast<const bf16x8*>(
            h1bf + (size_t)(mbase + ms * 32 + l31) * HD + c * 16 + oct * 8);
        acc[ms] = __builtin_amdgcn_mfma_f32_32x32x16_bf16(bfr, a, acc[ms], 0, 0, 0);
      }
    }
    // U2 tail (it=129): accT += mfma(A=bb, B=h2u resident)
    const char* bt2 = bt + 98304;
#pragma unroll
    for (int c = 0; c < 8; ++c) {
      bf16x8 bfr = __builtin_bit_cast(bf16x8, *reinterpret_cast<const uint4v*>(bt2 + c * 1024));
#pragma unroll
      for (int ms = 0; ms < 2; ++ms) {
        acc[ms] = __builtin_amdgcn_mfma_f32_32x32x16_bf16(
            bfr, __builtin_bit_cast(bf16x8, h2u[ms][c]), acc[ms], 0, 0, 0);
      }
    }
  }

  // epilogue: transposed regs regroup into aligned f32x4 row-chunks of out.
  // acc[ms][4q+j] -> out[mbase+ms*32+l31][n0w + 8q + 4*oct + j]
  float* my = part + (size_t)ks * PART_ELEMS;
#pragma unroll
  for (int ms = 0; ms < 2; ++ms) {
    float* rowp = my + (size_t)(mbase + ms * 32 + l31) * NOUT + n0w + 4 * oct;
#pragma unroll
    for (int qq = 0; qq < 4; ++qq) {
      f32x4 o;
      o[0] = acc[ms][qq * 4 + 0];
      o[1] = acc[ms][qq * 4 + 1];
      o[2] = acc[ms][qq * 4 + 2];
      o[3] = acc[ms][qq * 4 + 3];
      *reinterpret_cast<f32x4*>(rowp + 8 * qq) = o;
    }
  }
}

// ---------------- reduce: out = P0 + P1 (bias already in P1) ----------------
__global__ void reduce2(const float* __restrict__ part, float* __restrict__ out) {
  int i = blockIdx.x * 256 + threadIdx.x;          // 1,572,864 float4s
  float4 a = reinterpret_cast<const float4*>(part)[i];
  float4 b = reinterpret_cast<const float4*>(part + PART_ELEMS)[i];
  float4 o;
  o.x = a.x + b.x; o.y = a.y + b.y; o.z = a.z + b.z; o.w = a.w + b.w;
  reinterpret_cast<float4*>(out)[i] = o;
}

extern "C" void kernel_launch(void* const* d_in, const int* in_sizes, int n_in,
                              void* d_out, int out_size, void* d_ws, size_t ws_size,
                              hipStream_t stream) {
  const float* nh  = (const float*)d_in[0];   // (16384, 2, 128)
  const float* A   = (const float*)d_in[1];   // (128, 128, 384)
  const float* U1  = (const float*)d_in[2];   // (384, 128)
  const float* U2  = (const float*)d_in[3];   // (384, 128)
  const float* U2b = (const float*)d_in[4];   // (384,)

  char* ws = (char*)d_ws;
  ushort_t* pk   = (ushort_t*)(ws);                 // 130*98304    = 12,779,520 B
  ushort_t* h1bf = (ushort_t*)(ws + 12779520);      // 16384*128*2 =  4,194,304
  ushort_t* h2bf = (ushort_t*)(ws + 16973824);      //               4,194,304
  float*    h1tf = (float*)(ws + 21168128);         // 128*16384*4 =  8,388,608
  float*    part = (float*)(ws + 29556736);         // 2*25,165,824 = 50,331,648  (total ~79.9 MB)

  prep_all<<<dim3(772), 384, 0, stream>>>(A, U1, U2, nh, pk, h1bf, h2bf, h1tf);
  gemm_kernel<<<dim3(768), 512, 0, stream>>>(pk, h1bf, h2bf, h1tf, U2b, part);
  reduce2<<<dim3(6144), 256, 0, stream>>>(part, (float*)d_out);
}

// Round 2
// 308.386 us; speedup vs baseline: 1.8797x; 1.2997x over previous
//
#include <hip/hip_runtime.h>
#include <hip/hip_bf16.h>

typedef __attribute__((ext_vector_type(8))) short bf16x8;
typedef __attribute__((ext_vector_type(16))) float f32x16;
typedef __attribute__((ext_vector_type(4))) float f32x4;
typedef __attribute__((ext_vector_type(4))) unsigned int uint4v;
typedef unsigned short ushort_t;

#define N_NODES 16384
#define HD 128
#define NOUT 384
#define PART_ELEMS 6291456    // 16384*384
// packed B: pk[it][g][c][oct][l31][j]  it:0..129 (128,129 = U1,U2 tails)
//   byte offset = ((it*12+g)*16 + c*2 + oct)*512 + l31*16 + j*2 ; per-it = 98304 B

static __device__ __forceinline__ ushort_t f2bf(float f) {
  __hip_bfloat16 b = __float2bfloat16(f);
  return *reinterpret_cast<ushort_t*>(&b);
}

// ---------------- fused prep (384 threads/block) — unchanged ----------------
__global__ void prep_all(const float* __restrict__ A, const float* __restrict__ U1,
                         const float* __restrict__ U2, const float* __restrict__ nh,
                         ushort_t* __restrict__ pk, ushort_t* __restrict__ h1,
                         ushort_t* __restrict__ h2, float* __restrict__ h1tf) {
  __shared__ __align__(16) char smem[49152];
  const int b = blockIdx.x;
  const int t = threadIdx.x;

  if (b < 260) {
    short* spk = reinterpret_cast<short*>(smem);
    const int half = b & 1;
    const int gg = t >> 5, ll = t & 31;
    if (b < 256) {
      const int it = b >> 1;
      const size_t krow0 = (size_t)it * 128 + half * 64;
#pragma unroll 4
      for (int kl = 0; kl < 64; ++kl) {
        float v = A[(krow0 + kl) * NOUT + t];
        int cl = kl >> 4, oc = (kl >> 3) & 1, j = kl & 7;
        spk[(gg * 8 + cl * 2 + oc) * 256 + ll * 8 + j] = f2bf(v);
      }
    } else {
      const int u = (b - 256) >> 1;
      const float* U = u ? U2 : U1;
#pragma unroll 4
      for (int kl = 0; kl < 64; ++kl) {
        float v = U[(size_t)t * HD + half * 64 + kl];
        int cl = kl >> 4, oc = (kl >> 3) & 1, j = kl & 7;
        spk[(gg * 8 + cl * 2 + oc) * 256 + ll * 8 + j] = f2bf(v);
      }
    }
    __syncthreads();
    const int it_out = (b < 256) ? (b >> 1) : (128 + ((b - 256) >> 1));
    const int f = t * 64;
    const int g = f >> 11;
    const int inner = f & 2047;
    ushort_t* dst = pk + (size_t)it_out * 49152 + g * 4096 + half * 2048 + inner;
    const uint4* src = reinterpret_cast<const uint4*>(spk + f);
    uint4* d4 = reinterpret_cast<uint4*>(dst);
#pragma unroll
    for (int q = 0; q < 8; ++q) d4[q] = src[q];
  } else {
    if (t < 256) {
      float (*sm)[65] = reinterpret_cast<float(*)[65]>(smem);
      const int g = b - 260;            // 0..511
      const int mt = g & 255, jt = g >> 8;
      const int tx = t & 63, ty = t >> 6;
      const int m0 = mt * 64, j0 = jt * 64;
#pragma unroll
      for (int s = 0; s < 16; ++s) {
        int mm = ty + s * 4;
        float f1 = nh[(size_t)(m0 + mm) * 256 + j0 + tx];
        float f2 = nh[(size_t)(m0 + mm) * 256 + 128 + j0 + tx];
        h1[(size_t)(m0 + mm) * HD + j0 + tx] = f2bf(f1);
        h2[(size_t)(m0 + mm) * HD + j0 + tx] = f2bf(f2);
        sm[mm][tx] = f1;
      }
      __syncthreads();
#pragma unroll
      for (int s = 0; s < 16; ++s) {
        int jj = ty + s * 4;
        h1tf[(size_t)(j0 + jj) * N_NODES + m0 + tx] = sm[tx][jj];   // f32 transposed h1
      }
    }
  }
}

// ---------------- main GEMM: swapped-operand accumulation + explicit reg ping-pong ----
// accT[n,m] per lane: col(lane&31) = m-local, row(reg) = n-local.
// Per slice i: P^T = sum_c mfma(A=bb[c], B=h2u[ms][c]); acc[ms][r] += h1[m(lane), i] * P[r].
// Explicit 2-buffer register prefetch: loads for it+1 issue BEFORE it's MFMA block,
// so L2 latency (~300-500cy) hides under the 16-MFMA issue window (~515cy) x 2 waves/SIMD.
// Wave tile 64m x 32n. Block = 8 waves (4wm x 2wn) = 256m x 64n.
// grid = 64 Mt x 6 Nt x 2 ks = 768 blocks -> exactly 3 balanced rounds at 1 block/CU.
#define PK_STEP 98304

#define LOADB(BUF, S0, S1)                                            \
  do {                                                                \
    _Pragma("unroll")                                                 \
    for (int c = 0; c < 8; ++c)                                       \
      BUF[c] = *reinterpret_cast<const uint4v*>(pb + c * 1024);       \
    S0 = ph1[0];                                                      \
    S1 = ph1[32];                                                     \
    pb += PK_STEP;                                                    \
    ph1 += N_NODES;                                                   \
  } while (0)

#define COMPUTEB(BUF, S0, S1)                                         \
  do {                                                                \
    f32x16 P0 = vz, P1 = vz;                                          \
    _Pragma("unroll")                                                 \
    for (int c = 0; c < 8; ++c) {                                     \
      bf16x8 bfr = __builtin_bit_cast(bf16x8, BUF[c]);                \
      P0 = __builtin_amdgcn_mfma_f32_32x32x16_bf16(                   \
          bfr, __builtin_bit_cast(bf16x8, h2u[0][c]), P0, 0, 0, 0);   \
      P1 = __builtin_amdgcn_mfma_f32_32x32x16_bf16(                   \
          bfr, __builtin_bit_cast(bf16x8, h2u[1][c]), P1, 0, 0, 0);   \
    }                                                                 \
    _Pragma("unroll")                                                 \
    for (int r = 0; r < 16; ++r) {                                    \
      acc[0][r] += S0 * P0[r];                                        \
      acc[1][r] += S1 * P1[r];                                        \
    }                                                                 \
  } while (0)

__global__ __launch_bounds__(512, 2)
void gemm_kernel(const ushort_t* __restrict__ pk, const ushort_t* __restrict__ h1bf,
                 const ushort_t* __restrict__ h2bf, const float* __restrict__ h1tf,
                 const float* __restrict__ u2b, float* __restrict__ part) {
  const int tid = threadIdx.x;
  const int bid = blockIdx.x;
  // XCD-clustering swizzle (bijective: 768 = 8*96): each XCD sees <=2 (Nt,ks) slabs.
  const int v  = (bid & 7) * 96 + (bid >> 3);
  const int Mt = v & 63;
  const int q  = v >> 6;        // 0..11
  const int Nt = q >> 1;
  const int ks = q & 1;

  const int lane = tid & 63, wv = tid >> 6;
  const int l31 = lane & 31, oct = lane >> 5;
  const int wm = wv >> 1, wn = wv & 1;          // 4m x 2n wave grid
  const int mbase = Mt * 256 + wm * 64;
  const int n0w = Nt * 64 + wn * 32;
  const int g = Nt * 2 + wn;                    // 32-col group in pk

  // resident h2 fragments (used as MFMA B-operand): rows mbase+ms*32+l31
  uint4v h2u[2][8];
#pragma unroll
  for (int ms = 0; ms < 2; ++ms) {
    const ushort_t* hp = h2bf + (size_t)(mbase + ms * 32 + l31) * HD + oct * 8;
#pragma unroll
    for (int c = 0; c < 8; ++c)
      h2u[ms][c] = *reinterpret_cast<const uint4v*>(hp + c * 16);
  }

  // acc init (transposed layout): acc[ms][r] = out[mbase+ms*32+l31][n0w+(r&3)+8*(r>>2)+4*oct]
  f32x16 acc[2];
  if (ks) {
#pragma unroll
    for (int qq = 0; qq < 4; ++qq) {
      f32x4 bq = *reinterpret_cast<const f32x4*>(u2b + n0w + 8 * qq + 4 * oct);
#pragma unroll
      for (int j = 0; j < 4; ++j) { acc[0][qq * 4 + j] = bq[j]; acc[1][qq * 4 + j] = bq[j]; }
    }
  } else {
    acc[0] = (f32x16)(0.0f);
    acc[1] = (f32x16)(0.0f);
  }

  const int it0 = ks ? 65 : 0;
  const int it1 = ks ? 128 : 65;
  const int nit = it1 - it0;    // 65 or 63 — both odd

  const char* pb = reinterpret_cast<const char*>(pk) +
                   (size_t)it0 * PK_STEP + (size_t)(g * 16 + oct) * 512 + (size_t)l31 * 16;
  const float* ph1 = h1tf + (size_t)it0 * N_NODES + mbase + l31;

  const f32x16 vz = (f32x16)(0.0f);
  uint4v bA[8], bB[8];
  float s0A, s1A, s0B, s1B;

  // prologue: fill buffer A with slice it0
  LOADB(bA, s0A, s1A);

  // main: pairs. loads for the NEXT slice issue before the current MFMA block.
  const int pairs = (nit - 1) >> 1;
  for (int p = 0; p < pairs; ++p) {
    LOADB(bB, s0B, s1B);
    COMPUTEB(bA, s0A, s1A);
    LOADB(bA, s0A, s1A);
    COMPUTEB(bB, s0B, s1B);
  }
  // tail: last slice (nit is odd)
  COMPUTEB(bA, s0A, s1A);

  if (ks) {
    // U1 tail (it=128): accT += mfma(A=bb, B=h1 fragment)
    const char* bt = reinterpret_cast<const char*>(pk) +
                     (size_t)128 * PK_STEP + (size_t)(g * 16 + oct) * 512 + (size_t)l31 * 16;
#pragma unroll
    for (int c = 0; c < 8; ++c) {
      bf16x8 bfr = __builtin_bit_cast(bf16x8, *reinterpret_cast<const uint4v*>(bt + c * 1024));
#pragma unroll
      for (int ms = 0; ms < 2; ++ms) {
        bf16x8 a = *reinterpret_cast<const bf16x8*>(
            h1bf + (size_t)(mbase + ms * 32 + l31) * HD + c * 16 + oct * 8);
        acc[ms] = __builtin_amdgcn_mfma_f32_32x32x16_bf16(bfr, a, acc[ms], 0, 0, 0);
      }
    }
    // U2 tail (it=129): accT += mfma(A=bb, B=h2u resident)
    const char* bt2 = bt + PK_STEP;
#pragma unroll
    for (int c = 0; c < 8; ++c) {
      bf16x8 bfr = __builtin_bit_cast(bf16x8, *reinterpret_cast<const uint4v*>(bt2 + c * 1024));
#pragma unroll
      for (int ms = 0; ms < 2; ++ms) {
        acc[ms] = __builtin_amdgcn_mfma_f32_32x32x16_bf16(
            bfr, __builtin_bit_cast(bf16x8, h2u[ms][c]), acc[ms], 0, 0, 0);
      }
    }
  }

  // epilogue: transposed regs regroup into aligned f32x4 row-chunks of out.
  // acc[ms][4q+j] -> out[mbase+ms*32+l31][n0w + 8q + 4*oct + j]
  float* my = part + (size_t)ks * PART_ELEMS;
#pragma unroll
  for (int ms = 0; ms < 2; ++ms) {
    float* rowp = my + (size_t)(mbase + ms * 32 + l31) * NOUT + n0w + 4 * oct;
#pragma unroll
    for (int qq = 0; qq < 4; ++qq) {
      f32x4 o;
      o[0] = acc[ms][qq * 4 + 0];
      o[1] = acc[ms][qq * 4 + 1];
      o[2] = acc[ms][qq * 4 + 2];
      o[3] = acc[ms][qq * 4 + 3];
      *reinterpret_cast<f32x4*>(rowp + 8 * qq) = o;
    }
  }
}

// ---------------- reduce: out = P0 + P1 (bias already in P1) ----------------
__global__ void reduce2(const float* __restrict__ part, float* __restrict__ out) {
  int i = blockIdx.x * 256 + threadIdx.x;          // 1,572,864 float4s
  float4 a = reinterpret_cast<const float4*>(part)[i];
  float4 b = reinterpret_cast<const float4*>(part + PART_ELEMS)[i];
  float4 o;
  o.x = a.x + b.x; o.y = a.y + b.y; o.z = a.z + b.z; o.w = a.w + b.w;
  reinterpret_cast<float4*>(out)[i] = o;
}

extern "C" void kernel_launch(void* const* d_in, const int* in_sizes, int n_in,
                              void* d_out, int out_size, void* d_ws, size_t ws_size,
                              hipStream_t stream) {
  const float* nh  = (const float*)d_in[0];   // (16384, 2, 128)
  const float* A   = (const float*)d_in[1];   // (128, 128, 384)
  const float* U1  = (const float*)d_in[2];   // (384, 128)
  const float* U2  = (const float*)d_in[3];   // (384, 128)
  const float* U2b = (const float*)d_in[4];   // (384,)

  char* ws = (char*)d_ws;
  ushort_t* pk   = (ushort_t*)(ws);                 // 130*98304    = 12,779,520 B
  ushort_t* h1bf = (ushort_t*)(ws + 12779520);      // 16384*128*2 =  4,194,304
  ushort_t* h2bf = (ushort_t*)(ws + 16973824);      //               4,194,304
  float*    h1tf = (float*)(ws + 21168128);         // 128*16384*4 =  8,388,608
  float*    part = (float*)(ws + 29556736);         // 2*25,165,824 = 50,331,648  (total ~79.9 MB)

  prep_all<<<dim3(772), 384, 0, stream>>>(A, U1, U2, nh, pk, h1bf, h2bf, h1tf);
  gemm_kernel<<<dim3(768), 512, 0, stream>>>(pk, h1bf, h2bf, h1tf, U2b, part);
  reduce2<<<dim3(6144), 256, 0, stream>>>(part, (float*)d_out);
}